// Round 3
// baseline (28.343 us; speedup 1.0000x reference)
//
#include <hip/hip_runtime.h>

#define GROUPS 4
#define POINTS 120

typedef float f32x4 __attribute__((ext_vector_type(4)));

// out[i] = data[i] * (1 + dy_g) + dx_g, g = i % 4.
// dy_g = velo0_g*0.01*sin(theta0_g), dx_g = velo0_g*0.01*cos(theta0_g)
// (reference's _by_tanh degenerates to frame[0] because param.shape[1]-1 == 0).

__device__ __forceinline__ void compute_coeffs(const float* __restrict__ params,
                                               f32x4& A, f32x4& B)
{
#pragma unroll
    for (int g = 0; g < GROUPS; ++g) {
        float th0 = params[g * POINTS];                   // params[0][g][0]
        float v0  = params[GROUPS * POINTS + g * POINTS]; // params[1][g][0]
        float ds  = v0 * 0.01f;
        B[g] = ds * __cosf(th0);
        A[g] = 1.0f + ds * __sinf(th0);
    }
}

// Exact-cover kernel: gridDim.x*blockDim.x*K == n4. All K loads issued
// up-front (128 B in flight/thread), nontemporal stores (output never re-read;
// keep L3 for the constant input stream across graph replays).
template <int K>
__global__ __launch_bounds__(256) void foil_affine_k(
    const float* __restrict__ data,
    const float* __restrict__ params,
    float* __restrict__ out)
{
    f32x4 A, B;
    compute_coeffs(params, A, B);

    const f32x4* __restrict__ in4  = (const f32x4*)data;
    f32x4*       __restrict__ out4 = (f32x4*)out;

    const int nth  = gridDim.x * blockDim.x;
    const int base = blockIdx.x * blockDim.x + threadIdx.x;

    f32x4 v[K];
#pragma unroll
    for (int k = 0; k < K; ++k) v[k] = in4[base + k * nth];

#pragma unroll
    for (int k = 0; k < K; ++k) {
        f32x4 o;
        o.x = fmaf(v[k].x, A.x, B.x);
        o.y = fmaf(v[k].y, A.y, B.y);
        o.z = fmaf(v[k].z, A.z, B.z);
        o.w = fmaf(v[k].w, A.w, B.w);
        __builtin_nontemporal_store(o, &out4[base + k * nth]);
    }
}

// Fallback grid-stride kernel for sizes that don't divide.
__global__ __launch_bounds__(256) void foil_affine_gs(
    const float* __restrict__ data,
    const float* __restrict__ params,
    float* __restrict__ out,
    int n4)
{
    f32x4 A, B;
    compute_coeffs(params, A, B);

    const f32x4* __restrict__ in4  = (const f32x4*)data;
    f32x4*       __restrict__ out4 = (f32x4*)out;

    int stride = gridDim.x * blockDim.x;
    for (int i = blockIdx.x * blockDim.x + threadIdx.x; i < n4; i += stride) {
        f32x4 v = in4[i];
        f32x4 o;
        o.x = fmaf(v.x, A.x, B.x);
        o.y = fmaf(v.y, A.y, B.y);
        o.z = fmaf(v.z, A.z, B.z);
        o.w = fmaf(v.w, A.w, B.w);
        __builtin_nontemporal_store(o, &out4[i]);
    }
}

extern "C" void kernel_launch(void* const* d_in, const int* in_sizes, int n_in,
                              void* d_out, int out_size, void* d_ws, size_t ws_size,
                              hipStream_t stream) {
    const float* data   = (const float*)d_in[0];
    const float* params = (const float*)d_in[1];
    float* out = (float*)d_out;

    int n  = in_sizes[0];   // 4096*4096
    int n4 = n / 4;

    constexpr int K = 8;
    const int threads = 256;

    if (n % 4 == 0 && n4 % (threads * K) == 0) {
        int blocks = n4 / (threads * K);   // 2048 for 4096^2
        foil_affine_k<K><<<blocks, threads, 0, stream>>>(data, params, out);
    } else {
        int blocks = 2048;
        int needed = (n4 + threads - 1) / threads;
        if (blocks > needed) blocks = needed;
        foil_affine_gs<<<blocks, threads, 0, stream>>>(data, params, out, n4);
    }
}

// Round 4
// 27.437 us; speedup vs baseline: 1.0330x; 1.0330x over previous
//
#include <hip/hip_runtime.h>

#define GROUPS 4
#define POINTS 120

typedef float f32x4 __attribute__((ext_vector_type(4)));

// out[i] = data[i] * (1 + dy_g) + dx_g, g = i % 4.
// dy_g = velo0_g*0.01*sin(theta0_g), dx_g = velo0_g*0.01*cos(theta0_g)
// (reference's _by_tanh degenerates to frame[0] because param.shape[1]-1 == 0).
//
// NOTE: working set (64MB in + 64MB out) fits in the 256MB Infinity Cache.
// Regular write-back stores keep the output resident across graph replays;
// nontemporal stores forced an HBM write stream every replay and REGRESSED
// (R3: 28.3us vs R1: 26.2us). Keep cached stores.

__device__ __forceinline__ void compute_coeffs(const float* __restrict__ params,
                                               f32x4& A, f32x4& B)
{
#pragma unroll
    for (int g = 0; g < GROUPS; ++g) {
        float th0 = params[g * POINTS];                   // params[0][g][0]
        float v0  = params[GROUPS * POINTS + g * POINTS]; // params[1][g][0]
        float ds  = v0 * 0.01f;
        B[g] = ds * __cosf(th0);
        A[g] = 1.0f + ds * __sinf(th0);
    }
}

// Exact-cover kernel: gridDim.x*blockDim.x*K == n4. All K loads issued
// up-front (128 B in flight/thread), cached stores (L3 write-back).
template <int K>
__global__ __launch_bounds__(256) void foil_affine_k(
    const float* __restrict__ data,
    const float* __restrict__ params,
    float* __restrict__ out)
{
    f32x4 A, B;
    compute_coeffs(params, A, B);

    const f32x4* __restrict__ in4  = (const f32x4*)data;
    f32x4*       __restrict__ out4 = (f32x4*)out;

    const int nth  = gridDim.x * blockDim.x;
    const int base = blockIdx.x * blockDim.x + threadIdx.x;

    f32x4 v[K];
#pragma unroll
    for (int k = 0; k < K; ++k) v[k] = in4[base + k * nth];

#pragma unroll
    for (int k = 0; k < K; ++k) {
        f32x4 o;
        o.x = fmaf(v[k].x, A.x, B.x);
        o.y = fmaf(v[k].y, A.y, B.y);
        o.z = fmaf(v[k].z, A.z, B.z);
        o.w = fmaf(v[k].w, A.w, B.w);
        out4[base + k * nth] = o;
    }
}

// Fallback grid-stride kernel for sizes that don't divide.
__global__ __launch_bounds__(256) void foil_affine_gs(
    const float* __restrict__ data,
    const float* __restrict__ params,
    float* __restrict__ out,
    int n4)
{
    f32x4 A, B;
    compute_coeffs(params, A, B);

    const f32x4* __restrict__ in4  = (const f32x4*)data;
    f32x4*       __restrict__ out4 = (f32x4*)out;

    int stride = gridDim.x * blockDim.x;
    for (int i = blockIdx.x * blockDim.x + threadIdx.x; i < n4; i += stride) {
        f32x4 v = in4[i];
        f32x4 o;
        o.x = fmaf(v.x, A.x, B.x);
        o.y = fmaf(v.y, A.y, B.y);
        o.z = fmaf(v.z, A.z, B.z);
        o.w = fmaf(v.w, A.w, B.w);
        out4[i] = o;
    }
}

extern "C" void kernel_launch(void* const* d_in, const int* in_sizes, int n_in,
                              void* d_out, int out_size, void* d_ws, size_t ws_size,
                              hipStream_t stream) {
    const float* data   = (const float*)d_in[0];
    const float* params = (const float*)d_in[1];
    float* out = (float*)d_out;

    int n  = in_sizes[0];   // 4096*4096
    int n4 = n / 4;

    constexpr int K = 8;
    const int threads = 256;

    if (n % 4 == 0 && n4 % (threads * K) == 0) {
        int blocks = n4 / (threads * K);   // 2048 for 4096^2
        foil_affine_k<K><<<blocks, threads, 0, stream>>>(data, params, out);
    } else {
        int blocks = 2048;
        int needed = (n4 + threads - 1) / threads;
        if (blocks > needed) blocks = needed;
        foil_affine_gs<<<blocks, threads, 0, stream>>>(data, params, out, n4);
    }
}

// Round 5
// 25.186 us; speedup vs baseline: 1.1254x; 1.0894x over previous
//
#include <hip/hip_runtime.h>

#define GROUPS 4
#define POINTS 120

typedef float f32x4 __attribute__((ext_vector_type(4)));

// out[i] = data[i] * (1 + dy_g) + dx_g, g = i % 4.
// dy_g = velo0_g*0.01*sin(theta0_g), dx_g = velo0_g*0.01*cos(theta0_g)
// (reference's _by_tanh degenerates to frame[0] because param.shape[1]-1 == 0).
//
// Measured plateau (~26-28us across R1/R3/R4 structures): 128MB RMW stream at
// ~5 TB/s effective. nt stores regressed (R3); K=8 MLP batching neutral (R4) —
// TLP from 8192 resident waves already saturates the memory system.

__device__ __forceinline__ void compute_coeffs(const float* __restrict__ params,
                                               f32x4& A, f32x4& B)
{
#pragma unroll
    for (int g = 0; g < GROUPS; ++g) {
        float th0 = params[g * POINTS];                   // params[0][g][0]
        float v0  = params[GROUPS * POINTS + g * POINTS]; // params[1][g][0]
        float ds  = v0 * 0.01f;
        B[g] = ds * __cosf(th0);
        A[g] = 1.0f + ds * __sinf(th0);
    }
}

__global__ __launch_bounds__(256) void foil_affine_gs(
    const float* __restrict__ data,
    const float* __restrict__ params,
    float* __restrict__ out,
    int n4)
{
    f32x4 A, B;
    compute_coeffs(params, A, B);

    const f32x4* __restrict__ in4  = (const f32x4*)data;
    f32x4*       __restrict__ out4 = (f32x4*)out;

    int stride = gridDim.x * blockDim.x;
    for (int i = blockIdx.x * blockDim.x + threadIdx.x; i < n4; i += stride) {
        f32x4 v = in4[i];
        f32x4 o;
        o.x = fmaf(v.x, A.x, B.x);
        o.y = fmaf(v.y, A.y, B.y);
        o.z = fmaf(v.z, A.z, B.z);
        o.w = fmaf(v.w, A.w, B.w);
        out4[i] = o;
    }
}

extern "C" void kernel_launch(void* const* d_in, const int* in_sizes, int n_in,
                              void* d_out, int out_size, void* d_ws, size_t ws_size,
                              hipStream_t stream) {
    const float* data   = (const float*)d_in[0];
    const float* params = (const float*)d_in[1];
    float* out = (float*)d_out;

    int n  = in_sizes[0];   // 4096*4096
    int n4 = n / 4;

    const int threads = 256;
    int blocks = 4096;      // 4 iters/thread at 4096^2; A/B vs R1's 2048x8
    int needed = (n4 + threads - 1) / threads;
    if (blocks > needed) blocks = needed;

    foil_affine_gs<<<blocks, threads, 0, stream>>>(data, params, out, n4);
}

// Round 6
// 24.451 us; speedup vs baseline: 1.1592x; 1.0300x over previous
//
#include <hip/hip_runtime.h>

#define GROUPS 4
#define POINTS 120

typedef float f32x4 __attribute__((ext_vector_type(4)));

// out[i] = data[i] * (1 + dy_g) + dx_g, g = i % 4.
// dy_g = velo0_g*0.01*sin(theta0_g), dx_g = velo0_g*0.01*cos(theta0_g)
// (reference's _by_tanh degenerates to frame[0] because param.shape[1]-1 == 0).
//
// Block-count ladder (grid-stride, 256 thr): 2048 blk = 26.2us, 4096 blk =
// 25.2us. nt stores regressed (28.3); K=8 reg batching neutral (27.4).
// This round: 8192 blk x 2 iters — endpoint of the same knob.

__device__ __forceinline__ void compute_coeffs(const float* __restrict__ params,
                                               f32x4& A, f32x4& B)
{
#pragma unroll
    for (int g = 0; g < GROUPS; ++g) {
        float th0 = params[g * POINTS];                   // params[0][g][0]
        float v0  = params[GROUPS * POINTS + g * POINTS]; // params[1][g][0]
        float ds  = v0 * 0.01f;
        B[g] = ds * __cosf(th0);
        A[g] = 1.0f + ds * __sinf(th0);
    }
}

__global__ __launch_bounds__(256) void foil_affine_gs(
    const float* __restrict__ data,
    const float* __restrict__ params,
    float* __restrict__ out,
    int n4)
{
    f32x4 A, B;
    compute_coeffs(params, A, B);

    const f32x4* __restrict__ in4  = (const f32x4*)data;
    f32x4*       __restrict__ out4 = (f32x4*)out;

    int stride = gridDim.x * blockDim.x;
    for (int i = blockIdx.x * blockDim.x + threadIdx.x; i < n4; i += stride) {
        f32x4 v = in4[i];
        f32x4 o;
        o.x = fmaf(v.x, A.x, B.x);
        o.y = fmaf(v.y, A.y, B.y);
        o.z = fmaf(v.z, A.z, B.z);
        o.w = fmaf(v.w, A.w, B.w);
        out4[i] = o;
    }
}

extern "C" void kernel_launch(void* const* d_in, const int* in_sizes, int n_in,
                              void* d_out, int out_size, void* d_ws, size_t ws_size,
                              hipStream_t stream) {
    const float* data   = (const float*)d_in[0];
    const float* params = (const float*)d_in[1];
    float* out = (float*)d_out;

    int n  = in_sizes[0];   // 4096*4096
    int n4 = n / 4;

    const int threads = 256;
    int blocks = 8192;      // 2 iters/thread at 4096^2
    int needed = (n4 + threads - 1) / threads;
    if (blocks > needed) blocks = needed;

    foil_affine_gs<<<blocks, threads, 0, stream>>>(data, params, out, n4);
}

// Round 7
// 24.086 us; speedup vs baseline: 1.1767x; 1.0152x over previous
//
#include <hip/hip_runtime.h>

#define GROUPS 4
#define POINTS 120

typedef float f32x4 __attribute__((ext_vector_type(4)));

// out[i] = data[i] * (1 + dy_g) + dx_g, g = i % 4.
// dy_g = velo0_g*0.01*sin(theta0_g), dx_g = velo0_g*0.01*cos(theta0_g)
// (reference's _by_tanh degenerates to frame[0] because param.shape[1]-1 == 0).
//
// Block-count ladder (grid-stride, 256 thr): 2048=26.2us, 4096=25.2us,
// 8192=24.5us. nt stores regressed (28.3); K=8 reg batching neutral (27.4).
// This round: 16384 blk x 1 float4/thread — loop removed entirely.

__device__ __forceinline__ void compute_coeffs(const float* __restrict__ params,
                                               f32x4& A, f32x4& B)
{
#pragma unroll
    for (int g = 0; g < GROUPS; ++g) {
        float th0 = params[g * POINTS];                   // params[0][g][0]
        float v0  = params[GROUPS * POINTS + g * POINTS]; // params[1][g][0]
        float ds  = v0 * 0.01f;
        B[g] = ds * __cosf(th0);
        A[g] = 1.0f + ds * __sinf(th0);
    }
}

// One float4 per thread; grid covers n4 exactly.
__global__ __launch_bounds__(256) void foil_affine_1(
    const float* __restrict__ data,
    const float* __restrict__ params,
    float* __restrict__ out)
{
    f32x4 A, B;
    compute_coeffs(params, A, B);

    const f32x4* __restrict__ in4  = (const f32x4*)data;
    f32x4*       __restrict__ out4 = (f32x4*)out;

    const int i = blockIdx.x * blockDim.x + threadIdx.x;
    f32x4 v = in4[i];
    f32x4 o;
    o.x = fmaf(v.x, A.x, B.x);
    o.y = fmaf(v.y, A.y, B.y);
    o.z = fmaf(v.z, A.z, B.z);
    o.w = fmaf(v.w, A.w, B.w);
    out4[i] = o;
}

// Fallback grid-stride for non-dividing sizes.
__global__ __launch_bounds__(256) void foil_affine_gs(
    const float* __restrict__ data,
    const float* __restrict__ params,
    float* __restrict__ out,
    int n4)
{
    f32x4 A, B;
    compute_coeffs(params, A, B);

    const f32x4* __restrict__ in4  = (const f32x4*)data;
    f32x4*       __restrict__ out4 = (f32x4*)out;

    int stride = gridDim.x * blockDim.x;
    for (int i = blockIdx.x * blockDim.x + threadIdx.x; i < n4; i += stride) {
        f32x4 v = in4[i];
        f32x4 o;
        o.x = fmaf(v.x, A.x, B.x);
        o.y = fmaf(v.y, A.y, B.y);
        o.z = fmaf(v.z, A.z, B.z);
        o.w = fmaf(v.w, A.w, B.w);
        out4[i] = o;
    }
}

extern "C" void kernel_launch(void* const* d_in, const int* in_sizes, int n_in,
                              void* d_out, int out_size, void* d_ws, size_t ws_size,
                              hipStream_t stream) {
    const float* data   = (const float*)d_in[0];
    const float* params = (const float*)d_in[1];
    float* out = (float*)d_out;

    int n  = in_sizes[0];   // 4096*4096
    int n4 = n / 4;

    const int threads = 256;

    if (n % 4 == 0 && n4 % threads == 0) {
        int blocks = n4 / threads;   // 16384 for 4096^2
        foil_affine_1<<<blocks, threads, 0, stream>>>(data, params, out);
    } else {
        int blocks = 8192;
        int needed = (n4 + threads - 1) / threads;
        if (blocks > needed) blocks = needed;
        foil_affine_gs<<<blocks, threads, 0, stream>>>(data, params, out, n4);
    }
}